// Round 11
// baseline (686.017 us; speedup 1.0000x reference)
//
#include <hip/hip_runtime.h>

#define D 128
#define HD 256
#define BN_EPS 1e-5f

typedef __attribute__((ext_vector_type(8))) _Float16 h8;
typedef __attribute__((ext_vector_type(8))) unsigned short us8;
typedef __attribute__((ext_vector_type(4))) float f32x4;

__device__ __forceinline__ float4 ldg4(const float* p) {
    return *reinterpret_cast<const float4*>(p);
}
// f32 <-> f16 bit helpers (RNE)
__device__ __forceinline__ unsigned short f2h_bits(float f) {
    union { _Float16 h; unsigned short u; } c; c.h = (_Float16)f; return c.u;
}
__device__ __forceinline__ float h2f(unsigned short b) {
    union { unsigned short u; _Float16 h; } c; c.u = b; return (float)c.h;
}

// ---------------------------------------------------------------------------
// K0: AtomEncoder -> f16 h  (hf[i] = f16(ae1[x0] + ae2[x1]))
// ---------------------------------------------------------------------------
__global__ __launch_bounds__(256) void k_atom(
    const int* __restrict__ x,
    const float* __restrict__ ae1, const float* __restrict__ ae2,
    unsigned short* __restrict__ hf, int N)
{
    int idx = blockIdx.x * 256 + threadIdx.x;
    int row = idx >> 5;
    int d   = (idx & 31) * 4;
    if (row >= N) return;
    int i0 = x[row * 2 + 0];
    int i1 = x[row * 2 + 1];
    float4 a = ldg4(ae1 + (size_t)i0 * D + d);
    float4 b = ldg4(ae2 + (size_t)i1 * D + d);
    ushort4 o = {f2h_bits(a.x + b.x), f2h_bits(a.y + b.y),
                 f2h_bits(a.z + b.z), f2h_bits(a.w + b.w)};
    *reinterpret_cast<ushort4*>(hf + (size_t)row * D + d) = o;
}

// ---------------------------------------------------------------------------
// CSR build 1: ONE atomic per edge (counts only; degree derived in scan1)
// ---------------------------------------------------------------------------
__global__ __launch_bounds__(256) void k_hist(
    const int* __restrict__ ei, const int* __restrict__ ea,
    int* __restrict__ counts, int E)
{
    int e = blockIdx.x * 256 + threadIdx.x;
    if (e >= E) return;
    int dst = ei[E + e];
    int c = ea[2 * e] * 3 + ea[2 * e + 1];
    atomicAdd(&counts[dst * 9 + c], 1);
}

// ---------------------------------------------------------------------------
// CSR build 2a/2b/2c: multi-block prefix sum; deg(i) = sum of counts[i][0..9)
// ---------------------------------------------------------------------------
__global__ __launch_bounds__(1024) void k_scan1(
    const int* __restrict__ counts,
    int* __restrict__ rowptr, int* __restrict__ cursor,
    int* __restrict__ bsum, int N)
{
    __shared__ int wsum[16];
    int t = threadIdx.x, lane = t & 63, w = t >> 6;
    int i = blockIdx.x * 1024 + t;
    int v = 0;
    if (i < N) {
        const int* cp = counts + (size_t)i * 9;
#pragma unroll
        for (int j = 0; j < 9; ++j) v += cp[j];
    }
    int incl = v;
#pragma unroll
    for (int off = 1; off < 64; off <<= 1) {
        int y = __shfl_up(incl, off);
        if (lane >= off) incl += y;
    }
    if (lane == 63) wsum[w] = incl;
    __syncthreads();
    if (t < 16) {
        int xv = wsum[t];
#pragma unroll
        for (int off = 1; off < 16; off <<= 1) {
            int y = __shfl_up(xv, off);
            if (t >= off) xv += y;
        }
        wsum[t] = xv;
    }
    __syncthreads();
    int woff = w ? wsum[w - 1] : 0;
    int full = woff + incl;
    if (i < N) { rowptr[i + 1] = full; cursor[i] = full - v; }
    if (t == 1023) bsum[blockIdx.x] = full;
}

__global__ __launch_bounds__(64) void k_scan2(
    const int* __restrict__ bsum, int* __restrict__ boff, int nchunks)
{
    int t = threadIdx.x;
    int carry = 0;
    for (int base = 0; base < nchunks; base += 64) {
        int idx = base + t;
        int v = (idx < nchunks) ? bsum[idx] : 0;
        int incl = v;
#pragma unroll
        for (int off = 1; off < 64; off <<= 1) {
            int y = __shfl_up(incl, off);
            if (t >= off) incl += y;
        }
        if (idx < nchunks) boff[idx] = carry + incl - v;
        carry += __shfl(incl, 63);
    }
}

__global__ __launch_bounds__(1024) void k_scan3(
    int* __restrict__ rowptr, int* __restrict__ cursor,
    const int* __restrict__ boff, int N)
{
    int t = threadIdx.x;
    int i = blockIdx.x * 1024 + t;
    int off = boff[blockIdx.x];
    if (i < N) { rowptr[i + 1] += off; cursor[i] += off; }
    if (blockIdx.x == 0 && t == 0) rowptr[0] = 0;
}

// ---------------------------------------------------------------------------
// CSR build 3: fill edge sources in CSR order
// ---------------------------------------------------------------------------
__global__ __launch_bounds__(256) void k_fill(
    const int* __restrict__ ei, int* __restrict__ cursor,
    int* __restrict__ esrc, int E)
{
    int e = blockIdx.x * 256 + threadIdx.x;
    if (e >= E) return;
    int dst = ei[E + e];
    int pos = atomicAdd(&cursor[dst], 1);
    esrc[pos] = ei[e];
}

// ---------------------------------------------------------------------------
// bec precompute
// ---------------------------------------------------------------------------
__global__ __launch_bounds__(256) void k_bec(
    const float* __restrict__ be1, const float* __restrict__ be2,
    float* __restrict__ bec)
{
    int idx = blockIdx.x * 256 + threadIdx.x;
    if (idx >= 5 * 10 * D) return;
    int d  = idx & (D - 1);
    int lc = idx >> 7;
    int l = lc / 10, c = lc % 10;
    int a0 = (c == 9) ? 6 : (c / 3);
    int a1 = (c == 9) ? 3 : (c % 3);
    bec[idx] = be1[((size_t)l * 7 + a0) * D + d] + be2[((size_t)l * 4 + a1) * D + d];
}

// ---------------------------------------------------------------------------
// Weight pack: single f16 per element, fragment-ordered for LDS staging.
// Per frag f: 64 lanes x 16B (h8) = 1024 B. 64 frags/layer = 64 KB.
// ---------------------------------------------------------------------------
__global__ __launch_bounds__(256) void k_wconv(
    const float* __restrict__ W1, const float* __restrict__ W2,
    unsigned short* __restrict__ W1p, unsigned short* __restrict__ W2p)
{
    int tid = blockIdx.x * 256 + threadIdx.x;
    if (tid >= 2 * 5 * 4096) return;
    bool isW2 = tid >= 5 * 4096;
    int r  = tid & 4095;
    int l  = (tid % (5 * 4096)) >> 12;
    int f  = r >> 6;
    int lane = r & 63;
    int l15 = lane & 15, l4 = lane >> 4;
    if (!isW2) {
        int nt = f >> 2, kk = f & 3;
        int n = nt * 16 + l15;
        int kbase = kk * 32 + l4 * 8;
        const float* src = W1 + ((size_t)l * D + kbase) * HD + n;
        unsigned short* out = W1p + (size_t)l * 32768 + (size_t)f * 512 + lane * 8;
#pragma unroll
        for (int j = 0; j < 8; ++j) out[j] = f2h_bits(src[(size_t)j * HD]);
    } else {
        int nt = f >> 3, kk = f & 7;
        int n = nt * 16 + l15;
        int kbase = kk * 32 + l4 * 8;
        const float* src = W2 + ((size_t)l * HD + kbase) * D + n;
        unsigned short* out = W2p + (size_t)l * 32768 + (size_t)f * 512 + lane * 8;
#pragma unroll
        for (int j = 0; j < 8; ++j) out[j] = f2h_bits(src[(size_t)j * D]);
    }
}

// ---------------------------------------------------------------------------
// Gather from f16 h (+ fused BN affine + relu of previous layer),
// emits f16 hi/lo agg. 16 lanes/node, ushort8 (16B) loads, 16 nodes/block.
// aggp row: 256 ushorts = [128 hi][128 lo].
// ---------------------------------------------------------------------------
template <int AFFINE>
__global__ __launch_bounds__(256) void k_gather(
    const unsigned short* __restrict__ hf, const int* __restrict__ rowptr,
    const int* __restrict__ esrc, const int* __restrict__ counts,
    const float* __restrict__ bec,
    const float* __restrict__ ss,
    unsigned short* __restrict__ aggp, int N)
{
    int g = threadIdx.x >> 4;
    int lane = threadIdx.x & 15;
    int d = lane * 8;                       // 8 f16 elems per lane
    int node = blockIdx.x * 16 + g;
    if (node >= N) return;

    float sc[8], sh[8];
    if (AFFINE) {
        *reinterpret_cast<float4*>(&sc[0]) = ldg4(ss + d);
        *reinterpret_cast<float4*>(&sc[4]) = ldg4(ss + d + 4);
        *reinterpret_cast<float4*>(&sh[0]) = ldg4(ss + D + d);
        *reinterpret_cast<float4*>(&sh[4]) = ldg4(ss + D + d + 4);
    }

    float acc[8];
    {
        us8 u = *reinterpret_cast<const us8*>(hf + (size_t)node * D + d);
#pragma unroll
        for (int j = 0; j < 8; ++j) {
            float v = h2f(u[j]);
            if (AFFINE) { v = fmaf(v, sc[j], sh[j]); v = v > 0.f ? v : 0.f; }
            acc[j] = v;
        }
    }
    {
        const float* bp = bec + 9 * D + d;
#pragma unroll
        for (int j = 0; j < 8; ++j) acc[j] += bp[j];
    }
#pragma unroll
    for (int c = 0; c < 9; ++c) {
        float fc = (float)counts[node * 9 + c];
        const float* bp = bec + c * D + d;
#pragma unroll
        for (int j = 0; j < 8; ++j) acc[j] = fmaf(fc, bp[j], acc[j]);
    }

    int beg = rowptr[node], end = rowptr[node + 1];
    int e = beg;
    for (; e + 3 < end; e += 4) {
        int s0 = esrc[e], s1 = esrc[e + 1], s2 = esrc[e + 2], s3 = esrc[e + 3];
        us8 u0 = *reinterpret_cast<const us8*>(hf + (size_t)s0 * D + d);
        us8 u1 = *reinterpret_cast<const us8*>(hf + (size_t)s1 * D + d);
        us8 u2 = *reinterpret_cast<const us8*>(hf + (size_t)s2 * D + d);
        us8 u3 = *reinterpret_cast<const us8*>(hf + (size_t)s3 * D + d);
#pragma unroll
        for (int j = 0; j < 8; ++j) {
            float v0 = h2f(u0[j]), v1 = h2f(u1[j]), v2 = h2f(u2[j]), v3 = h2f(u3[j]);
            if (AFFINE) {
                v0 = fmaf(v0, sc[j], sh[j]); v0 = v0 > 0.f ? v0 : 0.f;
                v1 = fmaf(v1, sc[j], sh[j]); v1 = v1 > 0.f ? v1 : 0.f;
                v2 = fmaf(v2, sc[j], sh[j]); v2 = v2 > 0.f ? v2 : 0.f;
                v3 = fmaf(v3, sc[j], sh[j]); v3 = v3 > 0.f ? v3 : 0.f;
            }
            acc[j] += (v0 + v1) + (v2 + v3);
        }
    }
    for (; e < end; ++e) {
        us8 u0 = *reinterpret_cast<const us8*>(hf + (size_t)esrc[e] * D + d);
#pragma unroll
        for (int j = 0; j < 8; ++j) {
            float v0 = h2f(u0[j]);
            if (AFFINE) { v0 = fmaf(v0, sc[j], sh[j]); v0 = v0 > 0.f ? v0 : 0.f; }
            acc[j] += v0;
        }
    }

    us8 hv, lv;
#pragma unroll
    for (int j = 0; j < 8; ++j) {
        unsigned short q = f2h_bits(acc[j]);
        hv[j] = q;
        lv[j] = f2h_bits(acc[j] - h2f(q));
    }
    unsigned short* op = aggp + (size_t)node * 256;
    *reinterpret_cast<us8*>(op + d) = hv;
    *reinterpret_cast<us8*>(op + D + d) = lv;
}

// ---------------------------------------------------------------------------
// M1: GEMM1 + bias + relu -> single-f16 hidden IN-PLACE in aggp.
// W1 (64 KB f16) in LDS; 256 thr = 4 waves (wave tile 16 rows), 782 blocks,
// 2 blocks/CU. WAR-safe: all A-frag loads precede stores via MFMA dep chain.
// ---------------------------------------------------------------------------
__global__ __launch_bounds__(256) void k_m1(
    unsigned short* aggp,                      // [N][256]: read hi|lo, write hidden
    const unsigned short* __restrict__ W1p,    // layer slice, 32768 ushorts
    const float* __restrict__ b1, int N)
{
    __shared__ uint4 wlds[4096];               // 64 KB
    int t = threadIdx.x;
    {
        const uint4* src = (const uint4*)W1p;
        for (int i = t; i < 4096; i += 256) wlds[i] = src[i];
    }
    __syncthreads();                           // no barriers after this

    int w = t >> 6, lane = t & 63;
    int l15 = lane & 15, l4 = lane >> 4;
    int tile = blockIdx.x * 4 + w;
    int row0 = tile * 16;
    if (row0 >= N) return;

    int arow = row0 + l15;                     // N % 16 == 0: always < N
    h8 aHi[4], aLo[4];
    {
        const unsigned short* ap = aggp + (size_t)arow * 256 + l4 * 8;
#pragma unroll
        for (int kk = 0; kk < 4; ++kk) {
            aHi[kk] = *reinterpret_cast<const h8*>(ap + kk * 32);
            aLo[kk] = *reinterpret_cast<const h8*>(ap + D + kk * 32);
        }
    }

    const char* wl = (const char*)wlds;
    int drow_base = row0 + (l4 << 2);

#pragma unroll
    for (int nt = 0; nt < 16; ++nt) {
        f32x4 a = f32x4{0.f, 0.f, 0.f, 0.f};
#pragma unroll
        for (int kk = 0; kk < 4; ++kk) {
            int fb = ((nt << 2) | kk) << 10;   // frag * 1024 B
            h8 bW = *reinterpret_cast<const h8*>(wl + fb + (lane << 4));
            a = __builtin_amdgcn_mfma_f32_16x16x32_f16(aHi[kk], bW, a, 0, 0, 0);
            a = __builtin_amdgcn_mfma_f32_16x16x32_f16(aLo[kk], bW, a, 0, 0, 0);
        }
        int col = (nt << 4) + l15;
        float bias = b1[col];
#pragma unroll
        for (int r = 0; r < 4; ++r) {
            float v = a[r] + bias;
            v = v > 0.f ? v : 0.f;
            aggp[(size_t)(drow_base + r) * 256 + col] = f2h_bits(v);
        }
    }
}

// ---------------------------------------------------------------------------
// M2: GEMM2 + bias + BN stats. W2 (64 KB f16) in LDS, single-f16 hidden from
// aggp read directly as A-frags (no unpack). Writes f16 h; fp32 h2 if LAST.
// ---------------------------------------------------------------------------
template <int LAST>
__global__ __launch_bounds__(256) void k_m2(
    const unsigned short* __restrict__ aggp,   // hidden, [N][256] f16
    unsigned short* __restrict__ hf,           // f16 h out
    float* h2,                                 // = hbuf (LAST only)
    const unsigned short* __restrict__ W2p,    // layer slice
    const float* __restrict__ b2,
    float* __restrict__ stats, int N)
{
    __shared__ uint4 wlds[4096];               // 64 KB
    __shared__ float s_sum[D], s_sq[D];
    int t = threadIdx.x;
    {
        const uint4* src = (const uint4*)W2p;
        for (int i = t; i < 4096; i += 256) wlds[i] = src[i];
    }
    if (t < D) { s_sum[t] = 0.f; s_sq[t] = 0.f; }
    __syncthreads();

    int w = t >> 6, lane = t & 63;
    int l15 = lane & 15, l4 = lane >> 4;
    int tile = blockIdx.x * 4 + w;
    int row0 = tile * 16;
    bool active = row0 < N;

    if (active) {
        int arow = row0 + l15;
        const unsigned short* ap = aggp + (size_t)arow * 256 + l4 * 8;
        const char* wl = (const char*)wlds;
        f32x4 acc2[8];
#pragma unroll
        for (int nt = 0; nt < 8; ++nt) acc2[nt] = f32x4{0.f, 0.f, 0.f, 0.f};

#pragma unroll
        for (int kk = 0; kk < 8; ++kk) {
            h8 hA = *reinterpret_cast<const h8*>(ap + kk * 32);
#pragma unroll
            for (int nt = 0; nt < 8; ++nt) {
                int fb = ((nt << 3) | kk) << 10;
                h8 bW = *reinterpret_cast<const h8*>(wl + fb + (lane << 4));
                acc2[nt] = __builtin_amdgcn_mfma_f32_16x16x32_f16(hA, bW, acc2[nt], 0, 0, 0);
            }
        }

        int drow_base = row0 + (l4 << 2);
#pragma unroll
        for (int nt = 0; nt < 8; ++nt) {
            int col = (nt << 4) + l15;
            float bias = b2[col];
            float cs = 0.f, cq = 0.f;
#pragma unroll
            for (int r = 0; r < 4; ++r) {
                int drow = drow_base + r;
                float v = acc2[nt][r] + bias;
                hf[(size_t)drow * D + col] = f2h_bits(v);
                if (LAST) h2[(size_t)drow * D + col] = v;
                cs += v; cq += v * v;
            }
            atomicAdd(&s_sum[col], cs);
            atomicAdd(&s_sq[col],  cq);
        }
    }
    __syncthreads();
    if (t < D) {
        atomicAdd(stats + t,     s_sum[t]);
        atomicAdd(stats + D + t, s_sq[t]);
    }
}

// ---------------------------------------------------------------------------
// BN prep: scale/shift from sums
// ---------------------------------------------------------------------------
__global__ __launch_bounds__(128) void k_bnprep(
    const float* __restrict__ stats,
    const float* __restrict__ gamma, const float* __restrict__ beta,
    float* __restrict__ ss, float inv_n)
{
    int d = threadIdx.x;
    float mu  = stats[d] * inv_n;
    float var = stats[D + d] * inv_n - mu * mu;
    float sc  = rsqrtf(var + BN_EPS) * gamma[d];
    ss[d]     = sc;
    ss[D + d] = beta[d] - mu * sc;
}

// ---------------------------------------------------------------------------
// Final BN (no relu), in-place on d_out
// ---------------------------------------------------------------------------
__global__ __launch_bounds__(256) void k_bnfinal(
    float* __restrict__ h, const float* __restrict__ ss, int N)
{
    int idx = blockIdx.x * 256 + threadIdx.x;
    int row = idx >> 5;
    int d   = (idx & 31) * 4;
    if (row >= N) return;
    float4 v  = ldg4(h + (size_t)row * D + d);
    float4 sc = ldg4(ss + d);
    float4 sh = ldg4(ss + D + d);
    float4 o;
    o.x = fmaf(v.x, sc.x, sh.x);
    o.y = fmaf(v.y, sc.y, sh.y);
    o.z = fmaf(v.z, sc.z, sh.z);
    o.w = fmaf(v.w, sc.w, sh.w);
    *reinterpret_cast<float4*>(h + (size_t)row * D + d) = o;
}

// ---------------------------------------------------------------------------
static inline size_t align16(size_t x) { return (x + 15) & ~(size_t)15; }

extern "C" void kernel_launch(void* const* d_in, const int* in_sizes, int n_in,
                              void* d_out, int out_size, void* d_ws, size_t ws_size,
                              hipStream_t stream)
{
    const int*   x     = (const int*)  d_in[0];
    const int*   ei    = (const int*)  d_in[1];
    const int*   ea    = (const int*)  d_in[2];
    const float* ae1   = (const float*)d_in[3];
    const float* ae2   = (const float*)d_in[4];
    const float* be1   = (const float*)d_in[5];   // [5,7,128]
    const float* be2   = (const float*)d_in[6];   // [5,4,128]
    const float* W1    = (const float*)d_in[7];   // [5,128,256]
    const float* b1    = (const float*)d_in[8];   // [5,256]
    const float* W2    = (const float*)d_in[9];   // [5,256,128]
    const float* b2    = (const float*)d_in[10];  // [5,128]
    const float* gamma = (const float*)d_in[11];  // [5,128]
    const float* beta  = (const float*)d_in[12];  // [5,128]

    const int N = in_sizes[0] / 2;
    const int E = in_sizes[1] / 2;

    float* hbuf = (float*)d_out;

    // ---- workspace layout (bytes) ----
    char* wsb = (char*)d_ws;
    size_t o = 0;
    int* rowptr = (int*)(wsb + o);          o += align16((size_t)(N + 1) * 4);
    int* counts = (int*)(wsb + o);          o += align16((size_t)N * 9 * 4);
    float* stats = (float*)(wsb + o);       o += align16((size_t)5 * 2 * D * 4);
    const size_t zero_bytes = o;
    int* cursor = (int*)(wsb + o);          o += align16((size_t)N * 4);
    int* esrc = (int*)(wsb + o);            o += align16((size_t)E * 4);
    int* bsum = (int*)(wsb + o);            o += align16(1024 * 4);
    int* boff = (int*)(wsb + o);            o += align16(1024 * 4);
    float* ss = (float*)(wsb + o);          o += align16((size_t)5 * 2 * D * 4);
    float* bec = (float*)(wsb + o);         o += align16((size_t)5 * 10 * D * 4);
    unsigned short* W1p = (unsigned short*)(wsb + o); o += align16((size_t)5 * 32768 * 2);
    unsigned short* W2p = (unsigned short*)(wsb + o); o += align16((size_t)5 * 32768 * 2);
    unsigned short* aggp = (unsigned short*)(wsb + o); o += align16((size_t)N * 256 * 2);
    unsigned short* hf16 = (unsigned short*)(wsb + o); o += align16((size_t)N * D * 2);

    hipMemsetAsync(wsb, 0, zero_bytes, stream);

    const dim3 blk(256);
    const int nb_nodes  = (N * 32 + 255) / 256;
    const int nb_edges  = (E + 255) / 256;
    const int nchunks   = (N + 1023) / 1024;
    const int nb_gather = (N + 15) / 16;
    const int ntiles    = (N + 15) / 16;
    const int nb_m      = (ntiles + 3) / 4;     // 4 waves/block, 256 thr
    const float inv_n   = 1.0f / (float)N;

    k_atom<<<nb_nodes, blk, 0, stream>>>(x, ae1, ae2, hf16, N);
    k_hist<<<nb_edges, blk, 0, stream>>>(ei, ea, counts, E);
    k_scan1<<<nchunks, 1024, 0, stream>>>(counts, rowptr, cursor, bsum, N);
    k_scan2<<<1, 64, 0, stream>>>(bsum, boff, nchunks);
    k_scan3<<<nchunks, 1024, 0, stream>>>(rowptr, cursor, boff, N);
    k_fill<<<nb_edges, blk, 0, stream>>>(ei, cursor, esrc, E);
    k_bec<<<(5 * 10 * D + 255) / 256, blk, 0, stream>>>(be1, be2, bec);
    k_wconv<<<(2 * 5 * 4096 + 255) / 256, blk, 0, stream>>>(W1, W2, W1p, W2p);

    for (int l = 0; l < 5; ++l) {
        float* st = stats + (size_t)l * 2 * D;
        const float* becl = bec + (size_t)l * 10 * D;
        if (l == 0) {
            k_gather<0><<<nb_gather, blk, 0, stream>>>(
                hf16, rowptr, esrc, counts, becl, nullptr, aggp, N);
        } else {
            k_gather<1><<<nb_gather, blk, 0, stream>>>(
                hf16, rowptr, esrc, counts, becl, ss + (size_t)(l - 1) * 2 * D, aggp, N);
        }
        k_m1<<<nb_m, blk, 0, stream>>>(
            aggp, W1p + (size_t)l * 32768, b1 + (size_t)l * HD, N);
        if (l < 4) {
            k_m2<0><<<nb_m, blk, 0, stream>>>(
                aggp, hf16, hbuf,
                W2p + (size_t)l * 32768, b2 + (size_t)l * D, st, N);
        } else {
            k_m2<1><<<nb_m, blk, 0, stream>>>(
                aggp, hf16, hbuf,
                W2p + (size_t)l * 32768, b2 + (size_t)l * D, st, N);
        }
        k_bnprep<<<1, 128, 0, stream>>>(st, gamma + (size_t)l * D,
                                        beta + (size_t)l * D,
                                        ss + (size_t)l * 2 * D, inv_n);
    }
    k_bnfinal<<<nb_nodes, blk, 0, stream>>>(hbuf, ss + (size_t)4 * 2 * D, N);
}

// Round 12
// 634.143 us; speedup vs baseline: 1.0818x; 1.0818x over previous
//
#include <hip/hip_runtime.h>

#define D 128
#define HD 256
#define BN_EPS 1e-5f

typedef __attribute__((ext_vector_type(8))) _Float16 h8;
typedef __attribute__((ext_vector_type(8))) unsigned short us8;
typedef __attribute__((ext_vector_type(4))) float f32x4;

__device__ __forceinline__ float4 ldg4(const float* p) {
    return *reinterpret_cast<const float4*>(p);
}
// f32 <-> f16 bit helpers (RNE)
__device__ __forceinline__ unsigned short f2h_bits(float f) {
    union { _Float16 h; unsigned short u; } c; c.h = (_Float16)f; return c.u;
}
__device__ __forceinline__ float h2f(unsigned short b) {
    union { unsigned short u; _Float16 h; } c; c.u = b; return (float)c.h;
}

// ---------------------------------------------------------------------------
// K0: AtomEncoder -> f16 h  (hf[i] = f16(ae1[x0] + ae2[x1]))
// ---------------------------------------------------------------------------
__global__ __launch_bounds__(256) void k_atom(
    const int* __restrict__ x,
    const float* __restrict__ ae1, const float* __restrict__ ae2,
    unsigned short* __restrict__ hf, int N)
{
    int idx = blockIdx.x * 256 + threadIdx.x;
    int row = idx >> 5;
    int d   = (idx & 31) * 4;
    if (row >= N) return;
    int i0 = x[row * 2 + 0];
    int i1 = x[row * 2 + 1];
    float4 a = ldg4(ae1 + (size_t)i0 * D + d);
    float4 b = ldg4(ae2 + (size_t)i1 * D + d);
    ushort4 o = {f2h_bits(a.x + b.x), f2h_bits(a.y + b.y),
                 f2h_bits(a.z + b.z), f2h_bits(a.w + b.w)};
    *reinterpret_cast<ushort4*>(hf + (size_t)row * D + d) = o;
}

// ---------------------------------------------------------------------------
// CSR build 1: ONE atomic per edge (counts only; degree derived in scan1)
// ---------------------------------------------------------------------------
__global__ __launch_bounds__(256) void k_hist(
    const int* __restrict__ ei, const int* __restrict__ ea,
    int* __restrict__ counts, int E)
{
    int e = blockIdx.x * 256 + threadIdx.x;
    if (e >= E) return;
    int dst = ei[E + e];
    int c = ea[2 * e] * 3 + ea[2 * e + 1];
    atomicAdd(&counts[dst * 9 + c], 1);
}

// ---------------------------------------------------------------------------
// CSR build 2a/2b/2c: multi-block prefix sum; deg(i) = sum of counts[i][0..9)
// ---------------------------------------------------------------------------
__global__ __launch_bounds__(1024) void k_scan1(
    const int* __restrict__ counts,
    int* __restrict__ rowptr, int* __restrict__ cursor,
    int* __restrict__ bsum, int N)
{
    __shared__ int wsum[16];
    int t = threadIdx.x, lane = t & 63, w = t >> 6;
    int i = blockIdx.x * 1024 + t;
    int v = 0;
    if (i < N) {
        const int* cp = counts + (size_t)i * 9;
#pragma unroll
        for (int j = 0; j < 9; ++j) v += cp[j];
    }
    int incl = v;
#pragma unroll
    for (int off = 1; off < 64; off <<= 1) {
        int y = __shfl_up(incl, off);
        if (lane >= off) incl += y;
    }
    if (lane == 63) wsum[w] = incl;
    __syncthreads();
    if (t < 16) {
        int xv = wsum[t];
#pragma unroll
        for (int off = 1; off < 16; off <<= 1) {
            int y = __shfl_up(xv, off);
            if (t >= off) xv += y;
        }
        wsum[t] = xv;
    }
    __syncthreads();
    int woff = w ? wsum[w - 1] : 0;
    int full = woff + incl;
    if (i < N) { rowptr[i + 1] = full; cursor[i] = full - v; }
    if (t == 1023) bsum[blockIdx.x] = full;
}

__global__ __launch_bounds__(64) void k_scan2(
    const int* __restrict__ bsum, int* __restrict__ boff, int nchunks)
{
    int t = threadIdx.x;
    int carry = 0;
    for (int base = 0; base < nchunks; base += 64) {
        int idx = base + t;
        int v = (idx < nchunks) ? bsum[idx] : 0;
        int incl = v;
#pragma unroll
        for (int off = 1; off < 64; off <<= 1) {
            int y = __shfl_up(incl, off);
            if (t >= off) incl += y;
        }
        if (idx < nchunks) boff[idx] = carry + incl - v;
        carry += __shfl(incl, 63);
    }
}

__global__ __launch_bounds__(1024) void k_scan3(
    int* __restrict__ rowptr, int* __restrict__ cursor,
    const int* __restrict__ boff, int N)
{
    int t = threadIdx.x;
    int i = blockIdx.x * 1024 + t;
    int off = boff[blockIdx.x];
    if (i < N) { rowptr[i + 1] += off; cursor[i] += off; }
    if (blockIdx.x == 0 && t == 0) rowptr[0] = 0;
}

// ---------------------------------------------------------------------------
// CSR build 3: fill edge sources in CSR order
// ---------------------------------------------------------------------------
__global__ __launch_bounds__(256) void k_fill(
    const int* __restrict__ ei, int* __restrict__ cursor,
    int* __restrict__ esrc, int E)
{
    int e = blockIdx.x * 256 + threadIdx.x;
    if (e >= E) return;
    int dst = ei[E + e];
    int pos = atomicAdd(&cursor[dst], 1);
    esrc[pos] = ei[e];
}

// ---------------------------------------------------------------------------
// bec precompute
// ---------------------------------------------------------------------------
__global__ __launch_bounds__(256) void k_bec(
    const float* __restrict__ be1, const float* __restrict__ be2,
    float* __restrict__ bec)
{
    int idx = blockIdx.x * 256 + threadIdx.x;
    if (idx >= 5 * 10 * D) return;
    int d  = idx & (D - 1);
    int lc = idx >> 7;
    int l = lc / 10, c = lc % 10;
    int a0 = (c == 9) ? 6 : (c / 3);
    int a1 = (c == 9) ? 3 : (c % 3);
    bec[idx] = be1[((size_t)l * 7 + a0) * D + d] + be2[((size_t)l * 4 + a1) * D + d];
}

// ---------------------------------------------------------------------------
// Weight pack: single f16 per element, fragment-ordered for LDS staging.
// Per frag f: 64 lanes x 16B (h8) = 1024 B. 64 frags/layer = 64 KB.
// ---------------------------------------------------------------------------
__global__ __launch_bounds__(256) void k_wconv(
    const float* __restrict__ W1, const float* __restrict__ W2,
    unsigned short* __restrict__ W1p, unsigned short* __restrict__ W2p)
{
    int tid = blockIdx.x * 256 + threadIdx.x;
    if (tid >= 2 * 5 * 4096) return;
    bool isW2 = tid >= 5 * 4096;
    int r  = tid & 4095;
    int l  = (tid % (5 * 4096)) >> 12;
    int f  = r >> 6;
    int lane = r & 63;
    int l15 = lane & 15, l4 = lane >> 4;
    if (!isW2) {
        int nt = f >> 2, kk = f & 3;
        int n = nt * 16 + l15;
        int kbase = kk * 32 + l4 * 8;
        const float* src = W1 + ((size_t)l * D + kbase) * HD + n;
        unsigned short* out = W1p + (size_t)l * 32768 + (size_t)f * 512 + lane * 8;
#pragma unroll
        for (int j = 0; j < 8; ++j) out[j] = f2h_bits(src[(size_t)j * HD]);
    } else {
        int nt = f >> 3, kk = f & 7;
        int n = nt * 16 + l15;
        int kbase = kk * 32 + l4 * 8;
        const float* src = W2 + ((size_t)l * HD + kbase) * D + n;
        unsigned short* out = W2p + (size_t)l * 32768 + (size_t)f * 512 + lane * 8;
#pragma unroll
        for (int j = 0; j < 8; ++j) out[j] = f2h_bits(src[(size_t)j * D]);
    }
}

// ---------------------------------------------------------------------------
// Gather from f16 h (+ fused BN affine + relu of previous layer),
// emits f16 hi/lo agg. 16 lanes/node, ushort8 (16B) loads, 16 nodes/block.
// aggp row: 256 ushorts = [128 hi][128 lo].
// ---------------------------------------------------------------------------
template <int AFFINE>
__global__ __launch_bounds__(256) void k_gather(
    const unsigned short* __restrict__ hf, const int* __restrict__ rowptr,
    const int* __restrict__ esrc, const int* __restrict__ counts,
    const float* __restrict__ bec,
    const float* __restrict__ ss,
    unsigned short* __restrict__ aggp, int N)
{
    int g = threadIdx.x >> 4;
    int lane = threadIdx.x & 15;
    int d = lane * 8;                       // 8 f16 elems per lane
    int node = blockIdx.x * 16 + g;
    if (node >= N) return;

    float sc[8], sh[8];
    if (AFFINE) {
        *reinterpret_cast<float4*>(&sc[0]) = ldg4(ss + d);
        *reinterpret_cast<float4*>(&sc[4]) = ldg4(ss + d + 4);
        *reinterpret_cast<float4*>(&sh[0]) = ldg4(ss + D + d);
        *reinterpret_cast<float4*>(&sh[4]) = ldg4(ss + D + d + 4);
    }

    float acc[8];
    {
        us8 u = *reinterpret_cast<const us8*>(hf + (size_t)node * D + d);
#pragma unroll
        for (int j = 0; j < 8; ++j) {
            float v = h2f(u[j]);
            if (AFFINE) { v = fmaf(v, sc[j], sh[j]); v = v > 0.f ? v : 0.f; }
            acc[j] = v;
        }
    }
    {
        const float* bp = bec + 9 * D + d;
#pragma unroll
        for (int j = 0; j < 8; ++j) acc[j] += bp[j];
    }
#pragma unroll
    for (int c = 0; c < 9; ++c) {
        float fc = (float)counts[node * 9 + c];
        const float* bp = bec + c * D + d;
#pragma unroll
        for (int j = 0; j < 8; ++j) acc[j] = fmaf(fc, bp[j], acc[j]);
    }

    int beg = rowptr[node], end = rowptr[node + 1];
    int e = beg;
    for (; e + 3 < end; e += 4) {
        int s0 = esrc[e], s1 = esrc[e + 1], s2 = esrc[e + 2], s3 = esrc[e + 3];
        us8 u0 = *reinterpret_cast<const us8*>(hf + (size_t)s0 * D + d);
        us8 u1 = *reinterpret_cast<const us8*>(hf + (size_t)s1 * D + d);
        us8 u2 = *reinterpret_cast<const us8*>(hf + (size_t)s2 * D + d);
        us8 u3 = *reinterpret_cast<const us8*>(hf + (size_t)s3 * D + d);
#pragma unroll
        for (int j = 0; j < 8; ++j) {
            float v0 = h2f(u0[j]), v1 = h2f(u1[j]), v2 = h2f(u2[j]), v3 = h2f(u3[j]);
            if (AFFINE) {
                v0 = fmaf(v0, sc[j], sh[j]); v0 = v0 > 0.f ? v0 : 0.f;
                v1 = fmaf(v1, sc[j], sh[j]); v1 = v1 > 0.f ? v1 : 0.f;
                v2 = fmaf(v2, sc[j], sh[j]); v2 = v2 > 0.f ? v2 : 0.f;
                v3 = fmaf(v3, sc[j], sh[j]); v3 = v3 > 0.f ? v3 : 0.f;
            }
            acc[j] += (v0 + v1) + (v2 + v3);
        }
    }
    for (; e < end; ++e) {
        us8 u0 = *reinterpret_cast<const us8*>(hf + (size_t)esrc[e] * D + d);
#pragma unroll
        for (int j = 0; j < 8; ++j) {
            float v0 = h2f(u0[j]);
            if (AFFINE) { v0 = fmaf(v0, sc[j], sh[j]); v0 = v0 > 0.f ? v0 : 0.f; }
            acc[j] += v0;
        }
    }

    us8 hv, lv;
#pragma unroll
    for (int j = 0; j < 8; ++j) {
        unsigned short q = f2h_bits(acc[j]);
        hv[j] = q;
        lv[j] = f2h_bits(acc[j] - h2f(q));
    }
    unsigned short* op = aggp + (size_t)node * 256;
    *reinterpret_cast<us8*>(op + d) = hv;
    *reinterpret_cast<us8*>(op + D + d) = lv;
}

// ---------------------------------------------------------------------------
// M1: GEMM1 + bias + relu -> single-f16 hidden IN-PLACE in aggp.
// W1 (64 KB f16) in LDS; 1024 thr = 16 waves (one 64 KB stage amortized over
// 256 rows), grid = ceil(ntiles/16). WAR-safe: A-frag loads precede stores
// via the MFMA dependency chain. N % 16 == 0 assumed for arow bound.
// ---------------------------------------------------------------------------
__global__ __launch_bounds__(1024) void k_m1(
    unsigned short* aggp,                      // [N][256]: read hi|lo, write hidden
    const unsigned short* __restrict__ W1p,    // layer slice, 32768 ushorts
    const float* __restrict__ b1, int N)
{
    __shared__ uint4 wlds[4096];               // 64 KB
    int t = threadIdx.x;
    {
        const uint4* src = (const uint4*)W1p;
        for (int i = t; i < 4096; i += 1024) wlds[i] = src[i];
    }
    __syncthreads();                           // no barriers after this

    int w = t >> 6, lane = t & 63;
    int l15 = lane & 15, l4 = lane >> 4;
    int tile = blockIdx.x * 16 + w;
    int row0 = tile * 16;
    if (row0 >= N) return;

    int arow = row0 + l15;
    h8 aHi[4], aLo[4];
    {
        const unsigned short* ap = aggp + (size_t)arow * 256 + l4 * 8;
#pragma unroll
        for (int kk = 0; kk < 4; ++kk) {
            aHi[kk] = *reinterpret_cast<const h8*>(ap + kk * 32);
            aLo[kk] = *reinterpret_cast<const h8*>(ap + D + kk * 32);
        }
    }

    const char* wl = (const char*)wlds;
    int drow_base = row0 + (l4 << 2);

#pragma unroll
    for (int nt = 0; nt < 16; ++nt) {
        f32x4 a = f32x4{0.f, 0.f, 0.f, 0.f};
#pragma unroll
        for (int kk = 0; kk < 4; ++kk) {
            int fb = ((nt << 2) | kk) << 10;   // frag * 1024 B
            h8 bW = *reinterpret_cast<const h8*>(wl + fb + (lane << 4));
            a = __builtin_amdgcn_mfma_f32_16x16x32_f16(aHi[kk], bW, a, 0, 0, 0);
            a = __builtin_amdgcn_mfma_f32_16x16x32_f16(aLo[kk], bW, a, 0, 0, 0);
        }
        int col = (nt << 4) + l15;
        float bias = b1[col];
#pragma unroll
        for (int r = 0; r < 4; ++r) {
            float v = a[r] + bias;
            v = v > 0.f ? v : 0.f;
            aggp[(size_t)(drow_base + r) * 256 + col] = f2h_bits(v);
        }
    }
}

// ---------------------------------------------------------------------------
// M2: GEMM2 + bias + BN stats. W2 (64 KB f16) in LDS, single-f16 hidden from
// aggp read directly as A-frags (no unpack, 64 MFMA). 1024 thr = 16 waves.
// Writes f16 h; fp32 h2 only if LAST.
// ---------------------------------------------------------------------------
template <int LAST>
__global__ __launch_bounds__(1024) void k_m2(
    const unsigned short* __restrict__ aggp,   // hidden, [N][256] f16
    unsigned short* __restrict__ hf,           // f16 h out
    float* h2,                                 // = hbuf (LAST only)
    const unsigned short* __restrict__ W2p,    // layer slice
    const float* __restrict__ b2,
    float* __restrict__ stats, int N)
{
    __shared__ uint4 wlds[4096];               // 64 KB
    __shared__ float s_sum[D], s_sq[D];
    int t = threadIdx.x;
    {
        const uint4* src = (const uint4*)W2p;
        for (int i = t; i < 4096; i += 1024) wlds[i] = src[i];
    }
    if (t < D) { s_sum[t] = 0.f; s_sq[t] = 0.f; }
    __syncthreads();

    int w = t >> 6, lane = t & 63;
    int l15 = lane & 15, l4 = lane >> 4;
    int tile = blockIdx.x * 16 + w;
    int row0 = tile * 16;
    bool active = row0 < N;

    if (active) {
        int arow = row0 + l15;
        const unsigned short* ap = aggp + (size_t)arow * 256 + l4 * 8;
        const char* wl = (const char*)wlds;
        f32x4 acc2[8];
#pragma unroll
        for (int nt = 0; nt < 8; ++nt) acc2[nt] = f32x4{0.f, 0.f, 0.f, 0.f};

#pragma unroll
        for (int kk = 0; kk < 8; ++kk) {
            h8 hA = *reinterpret_cast<const h8*>(ap + kk * 32);
#pragma unroll
            for (int nt = 0; nt < 8; ++nt) {
                int fb = ((nt << 3) | kk) << 10;
                h8 bW = *reinterpret_cast<const h8*>(wl + fb + (lane << 4));
                acc2[nt] = __builtin_amdgcn_mfma_f32_16x16x32_f16(hA, bW, acc2[nt], 0, 0, 0);
            }
        }

        int drow_base = row0 + (l4 << 2);
#pragma unroll
        for (int nt = 0; nt < 8; ++nt) {
            int col = (nt << 4) + l15;
            float bias = b2[col];
            float cs = 0.f, cq = 0.f;
#pragma unroll
            for (int r = 0; r < 4; ++r) {
                int drow = drow_base + r;
                float v = acc2[nt][r] + bias;
                hf[(size_t)drow * D + col] = f2h_bits(v);
                if (LAST) h2[(size_t)drow * D + col] = v;
                cs += v; cq += v * v;
            }
            atomicAdd(&s_sum[col], cs);
            atomicAdd(&s_sq[col],  cq);
        }
    }
    __syncthreads();
    if (t < D) {
        atomicAdd(stats + t,     s_sum[t]);
        atomicAdd(stats + D + t, s_sq[t]);
    }
}

// ---------------------------------------------------------------------------
// BN prep: scale/shift from sums
// ---------------------------------------------------------------------------
__global__ __launch_bounds__(128) void k_bnprep(
    const float* __restrict__ stats,
    const float* __restrict__ gamma, const float* __restrict__ beta,
    float* __restrict__ ss, float inv_n)
{
    int d = threadIdx.x;
    float mu  = stats[d] * inv_n;
    float var = stats[D + d] * inv_n - mu * mu;
    float sc  = rsqrtf(var + BN_EPS) * gamma[d];
    ss[d]     = sc;
    ss[D + d] = beta[d] - mu * sc;
}

// ---------------------------------------------------------------------------
// Final BN (no relu), in-place on d_out
// ---------------------------------------------------------------------------
__global__ __launch_bounds__(256) void k_bnfinal(
    float* __restrict__ h, const float* __restrict__ ss, int N)
{
    int idx = blockIdx.x * 256 + threadIdx.x;
    int row = idx >> 5;
    int d   = (idx & 31) * 4;
    if (row >= N) return;
    float4 v  = ldg4(h + (size_t)row * D + d);
    float4 sc = ldg4(ss + d);
    float4 sh = ldg4(ss + D + d);
    float4 o;
    o.x = fmaf(v.x, sc.x, sh.x);
    o.y = fmaf(v.y, sc.y, sh.y);
    o.z = fmaf(v.z, sc.z, sh.z);
    o.w = fmaf(v.w, sc.w, sh.w);
    *reinterpret_cast<float4*>(h + (size_t)row * D + d) = o;
}

// ---------------------------------------------------------------------------
static inline size_t align16(size_t x) { return (x + 15) & ~(size_t)15; }

extern "C" void kernel_launch(void* const* d_in, const int* in_sizes, int n_in,
                              void* d_out, int out_size, void* d_ws, size_t ws_size,
                              hipStream_t stream)
{
    const int*   x     = (const int*)  d_in[0];
    const int*   ei    = (const int*)  d_in[1];
    const int*   ea    = (const int*)  d_in[2];
    const float* ae1   = (const float*)d_in[3];
    const float* ae2   = (const float*)d_in[4];
    const float* be1   = (const float*)d_in[5];   // [5,7,128]
    const float* be2   = (const float*)d_in[6];   // [5,4,128]
    const float* W1    = (const float*)d_in[7];   // [5,128,256]
    const float* b1    = (const float*)d_in[8];   // [5,256]
    const float* W2    = (const float*)d_in[9];   // [5,256,128]
    const float* b2    = (const float*)d_in[10];  // [5,128]
    const float* gamma = (const float*)d_in[11];  // [5,128]
    const float* beta  = (const float*)d_in[12];  // [5,128]

    const int N = in_sizes[0] / 2;
    const int E = in_sizes[1] / 2;

    float* hbuf = (float*)d_out;

    // ---- workspace layout (bytes) ----
    char* wsb = (char*)d_ws;
    size_t o = 0;
    int* rowptr = (int*)(wsb + o);          o += align16((size_t)(N + 1) * 4);
    int* counts = (int*)(wsb + o);          o += align16((size_t)N * 9 * 4);
    float* stats = (float*)(wsb + o);       o += align16((size_t)5 * 2 * D * 4);
    const size_t zero_bytes = o;
    int* cursor = (int*)(wsb + o);          o += align16((size_t)N * 4);
    int* esrc = (int*)(wsb + o);            o += align16((size_t)E * 4);
    int* bsum = (int*)(wsb + o);            o += align16(1024 * 4);
    int* boff = (int*)(wsb + o);            o += align16(1024 * 4);
    float* ss = (float*)(wsb + o);          o += align16((size_t)5 * 2 * D * 4);
    float* bec = (float*)(wsb + o);         o += align16((size_t)5 * 10 * D * 4);
    unsigned short* W1p = (unsigned short*)(wsb + o); o += align16((size_t)5 * 32768 * 2);
    unsigned short* W2p = (unsigned short*)(wsb + o); o += align16((size_t)5 * 32768 * 2);
    unsigned short* aggp = (unsigned short*)(wsb + o); o += align16((size_t)N * 256 * 2);
    unsigned short* hf16 = (unsigned short*)(wsb + o); o += align16((size_t)N * D * 2);

    hipMemsetAsync(wsb, 0, zero_bytes, stream);

    const dim3 blk(256);
    const int nb_nodes  = (N * 32 + 255) / 256;
    const int nb_edges  = (E + 255) / 256;
    const int nchunks   = (N + 1023) / 1024;
    const int nb_gather = (N + 15) / 16;
    const int ntiles    = (N + 15) / 16;
    const int nb_m      = (ntiles + 15) / 16;   // 16 waves/block, 1024 thr
    const float inv_n   = 1.0f / (float)N;

    k_atom<<<nb_nodes, blk, 0, stream>>>(x, ae1, ae2, hf16, N);
    k_hist<<<nb_edges, blk, 0, stream>>>(ei, ea, counts, E);
    k_scan1<<<nchunks, 1024, 0, stream>>>(counts, rowptr, cursor, bsum, N);
    k_scan2<<<1, 64, 0, stream>>>(bsum, boff, nchunks);
    k_scan3<<<nchunks, 1024, 0, stream>>>(rowptr, cursor, boff, N);
    k_fill<<<nb_edges, blk, 0, stream>>>(ei, cursor, esrc, E);
    k_bec<<<(5 * 10 * D + 255) / 256, blk, 0, stream>>>(be1, be2, bec);
    k_wconv<<<(2 * 5 * 4096 + 255) / 256, blk, 0, stream>>>(W1, W2, W1p, W2p);

    for (int l = 0; l < 5; ++l) {
        float* st = stats + (size_t)l * 2 * D;
        const float* becl = bec + (size_t)l * 10 * D;
        if (l == 0) {
            k_gather<0><<<nb_gather, blk, 0, stream>>>(
                hf16, rowptr, esrc, counts, becl, nullptr, aggp, N);
        } else {
            k_gather<1><<<nb_gather, blk, 0, stream>>>(
                hf16, rowptr, esrc, counts, becl, ss + (size_t)(l - 1) * 2 * D, aggp, N);
        }
        k_m1<<<nb_m, 1024, 0, stream>>>(
            aggp, W1p + (size_t)l * 32768, b1 + (size_t)l * HD, N);
        if (l < 4) {
            k_m2<0><<<nb_m, 1024, 0, stream>>>(
                aggp, hf16, hbuf,
                W2p + (size_t)l * 32768, b2 + (size_t)l * D, st, N);
        } else {
            k_m2<1><<<nb_m, 1024, 0, stream>>>(
                aggp, hf16, hbuf,
                W2p + (size_t)l * 32768, b2 + (size_t)l * D, st, N);
        }
        k_bnprep<<<1, 128, 0, stream>>>(st, gamma + (size_t)l * D,
                                        beta + (size_t)l * D,
                                        ss + (size_t)l * 2 * D, inv_n);
    }
    k_bnfinal<<<nb_nodes, blk, 0, stream>>>(hbuf, ss + (size_t)4 * 2 * D, N);
}